// Round 2
// baseline (283.187 us; speedup 1.0000x reference)
//
#include <hip/hip_runtime.h>
#include <hip/hip_bf16.h>
#include <math.h>

#define B_   128
#define T_   256
#define C_   384
#define H_   6
#define HS_  64
#define NTOK (B_*T_)          // 32768
#define NQKV (3*C_)           // 1152

typedef unsigned short u16;
typedef __attribute__((ext_vector_type(8))) short bf16x8;   // 8 bf16 in 4 VGPRs
typedef __attribute__((ext_vector_type(4))) float f32x4;

__device__ __forceinline__ u16 f2b(float f) {
    unsigned int u = __builtin_bit_cast(unsigned int, f);
    unsigned int r = (u + 0x7FFFu + ((u >> 16) & 1u)) >> 16;   // RNE
    return (u16)r;
}

__device__ __forceinline__ float fexp2(float x) {
#if __has_builtin(__builtin_amdgcn_exp2f)
    return __builtin_amdgcn_exp2f(x);
#else
    return exp2f(x);
#endif
}

// async global->LDS, 16B per lane.  LDS dst = wave-uniform base + lane*16B.
__device__ __forceinline__ void gl2lds16(const u16* g, u16* l) {
    __builtin_amdgcn_global_load_lds(
        (const __attribute__((address_space(1))) unsigned int*)g,
        (__attribute__((address_space(3))) unsigned int*)l, 16, 0, 0);
}

// log2(e) * (1/sqrt(64)) folded into q at the qkv epilogue; attn uses exp2.
#define QSCALE 0.180336880f

// ---------------------------------------------------------------------------
// Fused prep: x->bf16 (8/thread), Wp->bf16 (8/thread), Wcat_t build (1/thread)
// wct is HEAD-MAJOR: row n2 = h*192 + p*64 + d  (p in {q,k,v}).
// ---------------------------------------------------------------------------
#define J0_ (NTOK*C_/8)     // 1,572,864
#define J2_ (C_*C_/8)       // 18,432
#define J1_ (NQKV*C_)       // 442,368

__global__ __launch_bounds__(256) void prep(
    const float* __restrict__ x,  const float* __restrict__ Wq,
    const float* __restrict__ Wk, const float* __restrict__ Wv,
    const float* __restrict__ Wp,
    u16* __restrict__ xb, u16* __restrict__ wct, u16* __restrict__ wpb)
{
    int i = blockIdx.x * 256 + threadIdx.x;
    if (i < J0_) {
        const float4* s = (const float4*)x + (size_t)i * 2;
        float4 a = s[0], b = s[1];
        ushort4 o1, o2;
        o1.x = f2b(a.x); o1.y = f2b(a.y); o1.z = f2b(a.z); o1.w = f2b(a.w);
        o2.x = f2b(b.x); o2.y = f2b(b.y); o2.z = f2b(b.z); o2.w = f2b(b.w);
        ((ushort4*)xb)[(size_t)i * 2]     = o1;
        ((ushort4*)xb)[(size_t)i * 2 + 1] = o2;
    } else if (i < J0_ + J2_) {
        int j = i - J0_;
        const float4* s = (const float4*)Wp + (size_t)j * 2;
        float4 a = s[0], b = s[1];
        ushort4 o1, o2;
        o1.x = f2b(a.x); o1.y = f2b(a.y); o1.z = f2b(a.z); o1.w = f2b(a.w);
        o2.x = f2b(b.x); o2.y = f2b(b.y); o2.z = f2b(b.z); o2.w = f2b(b.w);
        ((ushort4*)wpb)[(size_t)j * 2]     = o1;
        ((ushort4*)wpb)[(size_t)j * 2 + 1] = o2;
    } else {
        int j = i - J0_ - J2_;
        if (j < J1_) {
            int n = j / C_, c = j % C_;
            int h = n / 192, rem = n % 192;       // head-major rows
            int p = rem >> 6, d = rem & 63;
            const float* W = (p == 0 ? Wq : (p == 1 ? Wk : Wv));
            wct[j] = f2b(W[(h * C_ + c) * HS_ + d]);
        }
    }
}

// ---------------------------------------------------------------------------
// Fused QKV projection + causal flash attention.  One block per (b,h).
// LDS 80 KB -> 2 blocks/CU (16 waves) so one block's staging drains overlap
// the other block's MFMA/softmax.
//   R0 [32K]: GEMM A-stage -> V^T[64][256] -> yt epilogue
//   R1 [32K]: GEMM B-stage -> Q-transfer (read to regs, then dead) -> K
//   R2 [16K]: per-wave P scratch, stride 64 + chunk-XOR swizzle
// Causal balance: wave w owns row-tiles {w*16, 240-w*16} -> exactly 5 S-tiles
// per wave (was 4/6 imbalance).
// ---------------------------------------------------------------------------
__global__ __launch_bounds__(512, 4) void qkv_attn(
    const u16* __restrict__ xb, const u16* __restrict__ wct,
    u16* __restrict__ yb)
{
    __shared__ __align__(16) u16 SM[40960];       // 80 KB
    u16* R0 = SM;                 // 32 KB
    u16* R1 = SM + 16384;         // 32 KB
    u16* R2 = SM + 32768;         // 16 KB

    const int gid = blockIdx.x;                    // 768 = 8 XCD * 96
    const int lin = (gid & 7) * 96 + (gid >> 3);   // bijective XCD swizzle
    const int b = lin / 6, h = lin % 6;

    const int tid = threadIdx.x;
    const int w = tid >> 6, lane = tid & 63;
    const int lm = lane & 15, qd = lane >> 4;
    const int wm = (w >> 1) * 64, wn = (w & 1) * 96;   // GEMM wave tile 64x96

    // ---- Phase 1: QKV GEMM ------------------------------------------------
    const int schunk = (lane & 7) ^ ((lane >> 3) & 7);   // XOR store swizzle
    const u16* gA = xb  + (size_t)(b * T_ + w * 32 + (lane >> 3)) * C_ + schunk * 8;
    const u16* gB = wct + (size_t)(h * 192 + w * 24 + (lane >> 3)) * C_ + schunk * 8;
    u16* lA = &R0[(w * 32) * 64];
    u16* lB = &R1[(w * 24) * 64];

    f32x4 acc[4][6];
    #pragma unroll
    for (int mi = 0; mi < 4; ++mi)
        #pragma unroll
        for (int ni = 0; ni < 6; ++ni)
            acc[mi][ni] = (f32x4){0.f, 0.f, 0.f, 0.f};

    for (int k0 = 0; k0 < C_; k0 += 64) {
        __syncthreads();
        #pragma unroll
        for (int j = 0; j < 4; ++j)                 // X tile: 256x64 bf16
            gl2lds16(gA + j * 8 * C_, lA + j * 8 * 64);
        #pragma unroll
        for (int j = 0; j < 3; ++j)                 // W tile: 192x64 bf16
            gl2lds16(gB + j * 8 * C_, lB + j * 8 * 64);
        gA += 64; gB += 64;
        __syncthreads();

        #pragma unroll
        for (int ks = 0; ks < 2; ++ks) {
            bf16x8 af[4], bfr[6];
            #pragma unroll
            for (int mi = 0; mi < 4; ++mi) {
                const int row = wm + mi * 16 + lm;
                const int sl = (ks * 4 + qd) ^ (lm & 7);
                af[mi] = *(const bf16x8*)&R0[row * 64 + sl * 8];
            }
            #pragma unroll
            for (int ni = 0; ni < 6; ++ni) {
                const int row = wn + ni * 16 + lm;
                const int sl = (ks * 4 + qd) ^ (lm & 7);
                bfr[ni] = *(const bf16x8*)&R1[row * 64 + sl * 8];
            }
            #pragma unroll
            for (int mi = 0; mi < 4; ++mi)
                #pragma unroll
                for (int ni = 0; ni < 6; ++ni)
                    acc[mi][ni] = __builtin_amdgcn_mfma_f32_16x16x32_bf16(
                        af[mi], bfr[ni], acc[mi][ni], 0, 0, 0);
        }
    }

    // ---- Phase 2a: Q -> R1 (transfer), V -> R0 ----------------------------
    __syncthreads();     // all stage-buffer reads drained; regions reusable
    #pragma unroll
    for (int mi = 0; mi < 4; ++mi) {
        const int t0 = wm + mi * 16 + qd * 4;
        #pragma unroll
        for (int ni = 0; ni < 6; ++ni) {
            const int n = wn + ni * 16 + lm;      // category uniform per (w,ni)
            if (n < 64) {                         // Q, scaled, row-swizzled
                #pragma unroll
                for (int r = 0; r < 4; ++r) {
                    const int t = t0 + r;
                    R1[t * 64 + (((n >> 3) ^ (t & 7)) << 3) + (n & 7)]
                        = f2b(acc[mi][ni][r] * QSCALE);
                }
            } else if (n >= 128) {                // V -> V^T[d][t], 8B packed
                const int d = n - 128;
                const int ch = t0 >> 3;           // t0 % 8 in {0,4}
                const int pos = (ch & 16) | ((ch ^ (d & 15)) & 15);
                ushort4 sv;
                sv.x = f2b(acc[mi][ni][0]); sv.y = f2b(acc[mi][ni][1]);
                sv.z = f2b(acc[mi][ni][2]); sv.w = f2b(acc[mi][ni][3]);
                *(ushort4*)&R0[d * 256 + pos * 8 + (t0 & 7)] = sv;
            }
        }
    }
    __syncthreads();

    // Q fragments to registers: wave w owns rows {w*16, 240-w*16} (+15)
    const int trg0 = w * 16;
    const int trg1 = 128 + (7 - w) * 16;
    bf16x8 aq[2][2];
    #pragma unroll
    for (int rg = 0; rg < 2; ++rg) {
        const int t = (rg ? trg1 : trg0) + lm;
        #pragma unroll
        for (int ks = 0; ks < 2; ++ks)
            aq[rg][ks] = *(const bf16x8*)
                &R1[t * 64 + (((ks * 4 + qd) ^ (t & 7)) << 3)];
    }
    __syncthreads();     // R1 now reusable: overwrite with K

    // ---- Phase 2b: K -> R1 ------------------------------------------------
    #pragma unroll
    for (int mi = 0; mi < 4; ++mi) {
        const int t0 = wm + mi * 16 + qd * 4;
        #pragma unroll
        for (int ni = 0; ni < 6; ++ni) {
            const int n = wn + ni * 16 + lm;
            if (n >= 64 && n < 128) {             // K, row-swizzled
                const int d = n - 64;
                #pragma unroll
                for (int r = 0; r < 4; ++r) {
                    const int t = t0 + r;
                    R1[t * 64 + (((d >> 3) ^ (t & 7)) << 3) + (d & 7)]
                        = f2b(acc[mi][ni][r]);
                }
            }
        }
    }
    __syncthreads();

    // ---- Phase 3: causal attention, all K/V in LDS ------------------------
    f32x4 oacc[2][4];
    float ms[2][4], ls[2][4];
    #pragma unroll
    for (int rg = 0; rg < 2; ++rg) {
        #pragma unroll
        for (int ni = 0; ni < 4; ++ni) oacc[rg][ni] = (f32x4){0.f, 0.f, 0.f, 0.f};
        #pragma unroll
        for (int r = 0; r < 4; ++r) { ms[rg][r] = -INFINITY; ls[rg][r] = 0.f; }
    }

    u16* Pw = R2 + w * 1024;     // 16x64 u16 per wave, chunk-XOR swizzled

    #pragma unroll
    for (int rg = 0; rg < 2; ++rg) {
        const int trg = rg ? trg1 : trg0;
        const int kmax = (trg + 15) >> 6;
        for (int kt = 0; kt <= kmax; ++kt) {
            const int j0 = kt * 64;
            const bool needmask = (j0 + 63 > trg);

            // S = Q K^T  (16 x 64)
            f32x4 st[4];
            #pragma unroll
            for (int ni = 0; ni < 4; ++ni) st[ni] = (f32x4){0.f, 0.f, 0.f, 0.f};
            #pragma unroll
            for (int ks = 0; ks < 2; ++ks) {
                #pragma unroll
                for (int ni = 0; ni < 4; ++ni) {
                    const int krow = j0 + ni * 16 + lm;
                    const int sl = (ks * 4 + qd) ^ (lm & 7);
                    bf16x8 bk = *(const bf16x8*)&R1[krow * 64 + sl * 8];
                    st[ni] = __builtin_amdgcn_mfma_f32_16x16x32_bf16(
                        aq[rg][ks], bk, st[ni], 0, 0, 0);
                }
            }

            // online softmax (base-2; q pre-scaled by log2e/8)
            float vals[4][4], rowmax[4];
            #pragma unroll
            for (int r = 0; r < 4; ++r) rowmax[r] = -INFINITY;
            #pragma unroll
            for (int ni = 0; ni < 4; ++ni) {
                const int s_g = j0 + ni * 16 + lm;
                #pragma unroll
                for (int r = 0; r < 4; ++r) {
                    float sc = st[ni][r];
                    if (needmask) {
                        const int t_g = trg + qd * 4 + r;
                        sc = (s_g > t_g) ? -1e30f : sc;
                    }
                    vals[ni][r] = sc;
                    rowmax[r] = fmaxf(rowmax[r], sc);
                }
            }
            #pragma unroll
            for (int msk = 1; msk <= 8; msk <<= 1)
                #pragma unroll
                for (int r = 0; r < 4; ++r)
                    rowmax[r] = fmaxf(rowmax[r], __shfl_xor(rowmax[r], msk, 64));

            float corr[4], rowsum[4];
            #pragma unroll
            for (int r = 0; r < 4; ++r) {
                const float mn = fmaxf(ms[rg][r], rowmax[r]);
                corr[r] = fexp2(ms[rg][r] - mn);
                ms[rg][r] = mn;
                rowsum[r] = 0.f;
            }
            #pragma unroll
            for (int ni = 0; ni < 4; ++ni) {
                #pragma unroll
                for (int r = 0; r < 4; ++r) {
                    const float pv = fexp2(vals[ni][r] - ms[rg][r]);
                    rowsum[r] += pv;
                    const int prow = qd * 4 + r;
                    const int pcol = ni * 16 + lm;
                    const int pch  = (pcol >> 3) ^ (prow & 7);
                    Pw[prow * 64 + pch * 8 + (pcol & 7)] = f2b(pv);
                }
            }
            #pragma unroll
            for (int msk = 1; msk <= 8; msk <<= 1)
                #pragma unroll
                for (int r = 0; r < 4; ++r)
                    rowsum[r] += __shfl_xor(rowsum[r], msk, 64);
            #pragma unroll
            for (int r = 0; r < 4; ++r) ls[rg][r] = ls[rg][r] * corr[r] + rowsum[r];
            #pragma unroll
            for (int ni = 0; ni < 4; ++ni)
                #pragma unroll
                for (int r = 0; r < 4; ++r)
                    oacc[rg][ni][r] *= corr[r];

            // PV: P via per-wave LDS (in-order DS pipe, no barrier)
            #pragma unroll
            for (int ks = 0; ks < 2; ++ks) {
                const int rch = (ks * 4 + qd) ^ (lm & 7);
                bf16x8 pa = *(const bf16x8*)&Pw[lm * 64 + rch * 8];
                #pragma unroll
                for (int ni = 0; ni < 4; ++ni) {
                    const int d = ni * 16 + lm;
                    const int cj = kt * 8 + ks * 4 + qd;
                    const int pos = (cj & 16) | ((cj ^ (d & 15)) & 15);
                    bf16x8 bv = *(const bf16x8*)&R0[d * 256 + pos * 8];
                    oacc[rg][ni] = __builtin_amdgcn_mfma_f32_16x16x32_bf16(
                        pa, bv, oacc[rg][ni], 0, 0, 0);
                }
            }
        }
    }

    // ---- Phase 4: rescale, transpose via LDS, coalesced stores ------------
    __syncthreads();
    u16 (*yt)[72] = (u16(*)[72])SM;     // 256x72 u16 = 36 KB (R0 + head of R1)
    #pragma unroll
    for (int rg = 0; rg < 2; ++rg) {
        const int trow = (rg ? trg1 : trg0) + qd * 4;
        #pragma unroll
        for (int r = 0; r < 4; ++r) {
            const float inv = 1.f / ls[rg][r];
            #pragma unroll
            for (int ni = 0; ni < 4; ++ni)
                yt[trow + r][ni * 16 + lm] = f2b(oacc[rg][ni][r] * inv);
        }
    }
    __syncthreads();
    #pragma unroll
    for (int rr = 0; rr < 4; ++rr) {
        const int row = rr * 64 + (tid >> 3);
        const int col = (tid & 7) * 8;
        bf16x8 vv = *(const bf16x8*)&yt[row][col];
        *(bf16x8*)(yb + ((size_t)(b * T_ + row)) * C_ + h * 64 + col) = vv;
    }
}

// ---------------------------------------------------------------------------
// Kernel 3: output projection.  yb[32768x384] @ wpb^T + bp -> fp32 out.
// 512 threads, 256x128 tile, XCD-affine, fp32 LDS-transpose epilogue.
// ---------------------------------------------------------------------------
__global__ __launch_bounds__(512, 4) void gemm_proj(
    const u16* __restrict__ yb, const u16* __restrict__ wpb,
    const float* __restrict__ bp, float* __restrict__ out)
{
    __shared__ __align__(16) u16 SMEM[256 * 64 + 128 * 64];   // 48 KB
    u16* As = SMEM;
    u16* Bs = SMEM + 256 * 64;

    const int gid  = blockIdx.x;
    const int xcd  = gid & 7;
    const int j_   = gid >> 3;            // 0..47
    const int colb = j_ % 3;
    const int rowb = (j_ / 3) * 8 + xcd;  // 0..127
    const int m0g  = rowb * 256;
    const int n0g  = colb * 128;

    const int tid = threadIdx.x;
    const int w = tid >> 6, lane = tid & 63;
    const int lm = lane & 15, qd = lane >> 4;
    const int wm = (w >> 1) * 64, wn = (w & 1) * 64;

    const int schunk = (lane & 7) ^ ((lane >> 3) & 7);
    const u16* gA = yb  + (size_t)(m0g + w * 32 + (lane >> 3)) * C_ + schunk * 8;
    const u16* gB = wpb + (size_t)(n0g + w * 16 + (lane >> 3)) * C_ + schunk * 8;
    u16* lA = &As[(w * 32) * 64];
    u16* lB = &Bs[(w * 16) * 64];

    f32x4 acc[4][4];
    #pragma unroll
    for (int mi = 0; mi < 4; ++mi)
        #pragma unroll
        for (int ni = 0; ni < 4; ++ni)
            acc[mi][ni] = (f32x4){0.f, 0.f, 0.f, 0.f};

    for (int k0 = 0; k0 < C_; k0 += 64) {
        __syncthreads();
        #pragma unroll
        for (int j = 0; j < 4; ++j)
            gl2lds16(gA + j * 8 * C_, lA + j * 8 * 64);
        #pragma unroll
        for (int j = 0; j < 2; ++j)
            gl2lds16(gB + j * 8 * C_, lB + j * 8 * 64);
        gA += 64; gB += 64;
        __syncthreads();

        #pragma unroll
        for (int ks = 0; ks < 2; ++ks) {
            bf16x8 af[4], bfr[4];
            #pragma unroll
            for (int mi = 0; mi < 4; ++mi) {
                const int row = wm + mi * 16 + lm;
                const int sl = (ks * 4 + qd) ^ (lm & 7);
                af[mi] = *(const bf16x8*)&As[row * 64 + sl * 8];
            }
            #pragma unroll
            for (int ni = 0; ni < 4; ++ni) {
                const int row = wn + ni * 16 + lm;
                const int sl = (ks * 4 + qd) ^ (lm & 7);
                bfr[ni] = *(const bf16x8*)&Bs[row * 64 + sl * 8];
            }
            #pragma unroll
            for (int mi = 0; mi < 4; ++mi)
                #pragma unroll
                for (int ni = 0; ni < 4; ++ni)
                    acc[mi][ni] = __builtin_amdgcn_mfma_f32_16x16x32_bf16(
                        af[mi], bfr[ni], acc[mi][ni], 0, 0, 0);
        }
    }

    // fp32 LDS-transpose epilogue with fused bias
    float bpv[4];
    #pragma unroll
    for (int ni = 0; ni < 4; ++ni) bpv[ni] = bp[n0g + wn + ni * 16 + lm];

    float (*tb)[132] = (float(*)[132])SMEM;   // 64x132 f32 = 33.8 KB <= 48 KB
    const int rloc = tid >> 3;                // 0..63
    #pragma unroll
    for (int mi = 0; mi < 4; ++mi) {
        __syncthreads();
        #pragma unroll
        for (int ni = 0; ni < 4; ++ni)
            #pragma unroll
            for (int r = 0; r < 4; ++r)
                tb[(w >> 1) * 16 + qd * 4 + r][wn + ni * 16 + lm]
                    = acc[mi][ni][r] + bpv[ni];
        __syncthreads();
        const int m = m0g + (rloc >> 4) * 64 + mi * 16 + (rloc & 15);
        #pragma unroll
        for (int jj = 0; jj < 4; ++jj) {
            const int cc = (tid & 7) * 4 + jj * 32;
            float4 vv = *(const float4*)&tb[rloc][cc];
            *(float4*)(out + (size_t)m * C_ + n0g + cc) = vv;
        }
    }
}

// ---------------------------------------------------------------------------
extern "C" void kernel_launch(void* const* d_in, const int* in_sizes, int n_in,
                              void* d_out, int out_size, void* d_ws, size_t ws_size,
                              hipStream_t stream)
{
    const float* x  = (const float*)d_in[0];
    const float* Wq = (const float*)d_in[1];
    const float* Wk = (const float*)d_in[2];
    const float* Wv = (const float*)d_in[3];
    const float* Wp = (const float*)d_in[4];
    const float* bp = (const float*)d_in[5];
    float* out = (float*)d_out;

    u16* xb  = (u16*)d_ws;                         // 32768*384
    u16* wct = xb  + (size_t)NTOK * C_;            // 1152*384 (head-major)
    u16* wpb = wct + (size_t)NQKV * C_;            // 384*384
    u16* yb  = wpb + (size_t)C_ * C_;              // 32768*384

    const int prep_blocks = (J0_ + J2_ + J1_ + 255) / 256;
    hipLaunchKernelGGL(prep, dim3(prep_blocks), dim3(256), 0, stream,
                       x, Wq, Wk, Wv, Wp, xb, wct, wpb);

    hipLaunchKernelGGL(qkv_attn, dim3(B_ * H_), dim3(512), 0, stream,
                       xb, wct, yb);

    hipLaunchKernelGGL(gemm_proj, dim3((NTOK / 256) * (C_ / 128)), dim3(512), 0, stream,
                       yb, wpb, bp, out);
}

// Round 3
// 188.646 us; speedup vs baseline: 1.5012x; 1.5012x over previous
//
#include <hip/hip_runtime.h>
#include <hip/hip_bf16.h>
#include <math.h>

#define B_   128
#define T_   256
#define C_   384
#define H_   6
#define HS_  64
#define NTOK (B_*T_)          // 32768
#define NQKV (3*C_)           // 1152

typedef unsigned short u16;
typedef __attribute__((ext_vector_type(8))) short bf16x8;   // 8 bf16 in 4 VGPRs
typedef __attribute__((ext_vector_type(4))) float f32x4;

__device__ __forceinline__ u16 f2b(float f) {
    unsigned int u = __builtin_bit_cast(unsigned int, f);
    unsigned int r = (u + 0x7FFFu + ((u >> 16) & 1u)) >> 16;   // RNE
    return (u16)r;
}

__device__ __forceinline__ float fexp2(float x) {
#if __has_builtin(__builtin_amdgcn_exp2f)
    return __builtin_amdgcn_exp2f(x);
#else
    return exp2f(x);
#endif
}

// async global->LDS, 16B per lane.  LDS dst = wave-uniform base + lane*16B.
__device__ __forceinline__ void gl2lds16(const u16* g, u16* l) {
    __builtin_amdgcn_global_load_lds(
        (const __attribute__((address_space(1))) unsigned int*)g,
        (__attribute__((address_space(3))) unsigned int*)l, 16, 0, 0);
}

// log2(e) * (1/sqrt(64)) folded into q at the qkv epilogue; attn uses exp2.
#define QSCALE 0.180336880f

// ---------------------------------------------------------------------------
// Fused prep: x->bf16 (8/thread), Wp->bf16 (8/thread), Wcat_t build (1/thread)
// wct is HEAD-MAJOR: row n2 = h*192 + p*64 + d  (p in {q,k,v}).
// ---------------------------------------------------------------------------
#define J0_ (NTOK*C_/8)     // 1,572,864
#define J2_ (C_*C_/8)       // 18,432
#define J1_ (NQKV*C_)       // 442,368

__global__ __launch_bounds__(256) void prep(
    const float* __restrict__ x,  const float* __restrict__ Wq,
    const float* __restrict__ Wk, const float* __restrict__ Wv,
    const float* __restrict__ Wp,
    u16* __restrict__ xb, u16* __restrict__ wct, u16* __restrict__ wpb)
{
    int i = blockIdx.x * 256 + threadIdx.x;
    if (i < J0_) {
        const float4* s = (const float4*)x + (size_t)i * 2;
        float4 a = s[0], b = s[1];
        ushort4 o1, o2;
        o1.x = f2b(a.x); o1.y = f2b(a.y); o1.z = f2b(a.z); o1.w = f2b(a.w);
        o2.x = f2b(b.x); o2.y = f2b(b.y); o2.z = f2b(b.z); o2.w = f2b(b.w);
        ((ushort4*)xb)[(size_t)i * 2]     = o1;
        ((ushort4*)xb)[(size_t)i * 2 + 1] = o2;
    } else if (i < J0_ + J2_) {
        int j = i - J0_;
        const float4* s = (const float4*)Wp + (size_t)j * 2;
        float4 a = s[0], b = s[1];
        ushort4 o1, o2;
        o1.x = f2b(a.x); o1.y = f2b(a.y); o1.z = f2b(a.z); o1.w = f2b(a.w);
        o2.x = f2b(b.x); o2.y = f2b(b.y); o2.z = f2b(b.z); o2.w = f2b(b.w);
        ((ushort4*)wpb)[(size_t)j * 2]     = o1;
        ((ushort4*)wpb)[(size_t)j * 2 + 1] = o2;
    } else {
        int j = i - J0_ - J2_;
        if (j < J1_) {
            int n = j / C_, c = j % C_;
            int h = n / 192, rem = n % 192;       // head-major rows
            int p = rem >> 6, d = rem & 63;
            const float* W = (p == 0 ? Wq : (p == 1 ? Wk : Wv));
            wct[j] = f2b(W[(h * C_ + c) * HS_ + d]);
        }
    }
}

// ---------------------------------------------------------------------------
// Fused QKV projection + causal flash attention.  One block per (b,h).
// LDS 80 KB + VGPR<=128 -> 2 blocks/CU (16 waves): one block's staging drains
// overlap the other block's MFMA/softmax.
//   R0 [32K]: GEMM A-stage -> V^T[64][256] -> yt epilogue
//   R1 [32K]: GEMM B-stage -> Q-transfer (read to regs, then dead) -> K
//   R2 [16K]: per-wave P scratch, stride 64 + chunk-XOR swizzle
// Causal balance: wave w owns row-tiles {w*16, 240-w*16} -> exactly 5 S-tiles
// per wave.
// NOTE: launch_bounds must stay (512,2).  (512,4) made the compiler clamp to
// 64 VGPRs -> accumulator spill -> 485 MB of scratch HBM traffic (measured).
// With (512,2) the compiler picks ~96-104 VGPRs; 96<=128 still allows 4
// waves/SIMD so 2 blocks/CU is granted by HW at runtime.
// ---------------------------------------------------------------------------
__global__ __launch_bounds__(512, 2) void qkv_attn(
    const u16* __restrict__ xb, const u16* __restrict__ wct,
    u16* __restrict__ yb)
{
    __shared__ __align__(16) u16 SM[40960];       // 80 KB
    u16* R0 = SM;                 // 32 KB
    u16* R1 = SM + 16384;         // 32 KB
    u16* R2 = SM + 32768;         // 16 KB

    const int gid = blockIdx.x;                    // 768 = 8 XCD * 96
    const int lin = (gid & 7) * 96 + (gid >> 3);   // bijective XCD swizzle
    const int b = lin / 6, h = lin % 6;

    const int tid = threadIdx.x;
    const int w = tid >> 6, lane = tid & 63;
    const int lm = lane & 15, qd = lane >> 4;
    const int wm = (w >> 1) * 64, wn = (w & 1) * 96;   // GEMM wave tile 64x96

    // ---- Phase 1: QKV GEMM ------------------------------------------------
    const int schunk = (lane & 7) ^ ((lane >> 3) & 7);   // XOR store swizzle
    const u16* gA = xb  + (size_t)(b * T_ + w * 32 + (lane >> 3)) * C_ + schunk * 8;
    const u16* gB = wct + (size_t)(h * 192 + w * 24 + (lane >> 3)) * C_ + schunk * 8;
    u16* lA = &R0[(w * 32) * 64];
    u16* lB = &R1[(w * 24) * 64];

    f32x4 acc[4][6];
    #pragma unroll
    for (int mi = 0; mi < 4; ++mi)
        #pragma unroll
        for (int ni = 0; ni < 6; ++ni)
            acc[mi][ni] = (f32x4){0.f, 0.f, 0.f, 0.f};

    for (int k0 = 0; k0 < C_; k0 += 64) {
        __syncthreads();
        #pragma unroll
        for (int j = 0; j < 4; ++j)                 // X tile: 256x64 bf16
            gl2lds16(gA + j * 8 * C_, lA + j * 8 * 64);
        #pragma unroll
        for (int j = 0; j < 3; ++j)                 // W tile: 192x64 bf16
            gl2lds16(gB + j * 8 * C_, lB + j * 8 * 64);
        gA += 64; gB += 64;
        __syncthreads();

        #pragma unroll
        for (int ks = 0; ks < 2; ++ks) {
            bf16x8 af[4], bfr[6];
            #pragma unroll
            for (int mi = 0; mi < 4; ++mi) {
                const int row = wm + mi * 16 + lm;
                const int sl = (ks * 4 + qd) ^ (lm & 7);
                af[mi] = *(const bf16x8*)&R0[row * 64 + sl * 8];
            }
            #pragma unroll
            for (int ni = 0; ni < 6; ++ni) {
                const int row = wn + ni * 16 + lm;
                const int sl = (ks * 4 + qd) ^ (lm & 7);
                bfr[ni] = *(const bf16x8*)&R1[row * 64 + sl * 8];
            }
            #pragma unroll
            for (int mi = 0; mi < 4; ++mi)
                #pragma unroll
                for (int ni = 0; ni < 6; ++ni)
                    acc[mi][ni] = __builtin_amdgcn_mfma_f32_16x16x32_bf16(
                        af[mi], bfr[ni], acc[mi][ni], 0, 0, 0);
        }
    }

    // ---- Phase 2a: Q -> R1 (transfer), V -> R0 ----------------------------
    __syncthreads();     // all stage-buffer reads drained; regions reusable
    #pragma unroll
    for (int mi = 0; mi < 4; ++mi) {
        const int t0 = wm + mi * 16 + qd * 4;
        #pragma unroll
        for (int ni = 0; ni < 6; ++ni) {
            const int n = wn + ni * 16 + lm;      // category uniform per (w,ni)
            if (n < 64) {                         // Q, scaled, row-swizzled
                #pragma unroll
                for (int r = 0; r < 4; ++r) {
                    const int t = t0 + r;
                    R1[t * 64 + (((n >> 3) ^ (t & 7)) << 3) + (n & 7)]
                        = f2b(acc[mi][ni][r] * QSCALE);
                }
            } else if (n >= 128) {                // V -> V^T[d][t], 8B packed
                const int d = n - 128;
                const int ch = t0 >> 3;           // t0 % 8 in {0,4}
                const int pos = (ch & 16) | ((ch ^ (d & 15)) & 15);
                ushort4 sv;
                sv.x = f2b(acc[mi][ni][0]); sv.y = f2b(acc[mi][ni][1]);
                sv.z = f2b(acc[mi][ni][2]); sv.w = f2b(acc[mi][ni][3]);
                *(ushort4*)&R0[d * 256 + pos * 8 + (t0 & 7)] = sv;
            }
        }
    }
    __syncthreads();

    // Q fragments to registers: wave w owns rows {w*16, 240-w*16} (+15)
    const int trg0 = w * 16;
    const int trg1 = 128 + (7 - w) * 16;
    bf16x8 aq[2][2];
    #pragma unroll
    for (int rg = 0; rg < 2; ++rg) {
        const int t = (rg ? trg1 : trg0) + lm;
        #pragma unroll
        for (int ks = 0; ks < 2; ++ks)
            aq[rg][ks] = *(const bf16x8*)
                &R1[t * 64 + (((ks * 4 + qd) ^ (t & 7)) << 3)];
    }
    __syncthreads();     // R1 now reusable: overwrite with K

    // ---- Phase 2b: K -> R1 ------------------------------------------------
    #pragma unroll
    for (int mi = 0; mi < 4; ++mi) {
        const int t0 = wm + mi * 16 + qd * 4;
        #pragma unroll
        for (int ni = 0; ni < 6; ++ni) {
            const int n = wn + ni * 16 + lm;
            if (n >= 64 && n < 128) {             // K, row-swizzled
                const int d = n - 64;
                #pragma unroll
                for (int r = 0; r < 4; ++r) {
                    const int t = t0 + r;
                    R1[t * 64 + (((d >> 3) ^ (t & 7)) << 3) + (d & 7)]
                        = f2b(acc[mi][ni][r]);
                }
            }
        }
    }
    __syncthreads();

    // ---- Phase 3: causal attention, all K/V in LDS ------------------------
    f32x4 oacc[2][4];
    float ms[2][4], ls[2][4];
    #pragma unroll
    for (int rg = 0; rg < 2; ++rg) {
        #pragma unroll
        for (int ni = 0; ni < 4; ++ni) oacc[rg][ni] = (f32x4){0.f, 0.f, 0.f, 0.f};
        #pragma unroll
        for (int r = 0; r < 4; ++r) { ms[rg][r] = -INFINITY; ls[rg][r] = 0.f; }
    }

    u16* Pw = R2 + w * 1024;     // 16x64 u16 per wave, chunk-XOR swizzled

    #pragma unroll
    for (int rg = 0; rg < 2; ++rg) {
        const int trg = rg ? trg1 : trg0;
        const int kmax = (trg + 15) >> 6;
        for (int kt = 0; kt <= kmax; ++kt) {
            const int j0 = kt * 64;
            const bool needmask = (j0 + 63 > trg);

            // S = Q K^T  (16 x 64)
            f32x4 st[4];
            #pragma unroll
            for (int ni = 0; ni < 4; ++ni) st[ni] = (f32x4){0.f, 0.f, 0.f, 0.f};
            #pragma unroll
            for (int ks = 0; ks < 2; ++ks) {
                #pragma unroll
                for (int ni = 0; ni < 4; ++ni) {
                    const int krow = j0 + ni * 16 + lm;
                    const int sl = (ks * 4 + qd) ^ (lm & 7);
                    bf16x8 bk = *(const bf16x8*)&R1[krow * 64 + sl * 8];
                    st[ni] = __builtin_amdgcn_mfma_f32_16x16x32_bf16(
                        aq[rg][ks], bk, st[ni], 0, 0, 0);
                }
            }

            // online softmax (base-2; q pre-scaled by log2e/8)
            float vals[4][4], rowmax[4];
            #pragma unroll
            for (int r = 0; r < 4; ++r) rowmax[r] = -INFINITY;
            #pragma unroll
            for (int ni = 0; ni < 4; ++ni) {
                const int s_g = j0 + ni * 16 + lm;
                #pragma unroll
                for (int r = 0; r < 4; ++r) {
                    float sc = st[ni][r];
                    if (needmask) {
                        const int t_g = trg + qd * 4 + r;
                        sc = (s_g > t_g) ? -1e30f : sc;
                    }
                    vals[ni][r] = sc;
                    rowmax[r] = fmaxf(rowmax[r], sc);
                }
            }
            #pragma unroll
            for (int msk = 1; msk <= 8; msk <<= 1)
                #pragma unroll
                for (int r = 0; r < 4; ++r)
                    rowmax[r] = fmaxf(rowmax[r], __shfl_xor(rowmax[r], msk, 64));

            float corr[4], rowsum[4];
            #pragma unroll
            for (int r = 0; r < 4; ++r) {
                const float mn = fmaxf(ms[rg][r], rowmax[r]);
                corr[r] = fexp2(ms[rg][r] - mn);
                ms[rg][r] = mn;
                rowsum[r] = 0.f;
            }
            #pragma unroll
            for (int ni = 0; ni < 4; ++ni) {
                #pragma unroll
                for (int r = 0; r < 4; ++r) {
                    const float pv = fexp2(vals[ni][r] - ms[rg][r]);
                    rowsum[r] += pv;
                    const int prow = qd * 4 + r;
                    const int pcol = ni * 16 + lm;
                    const int pch  = (pcol >> 3) ^ (prow & 7);
                    Pw[prow * 64 + pch * 8 + (pcol & 7)] = f2b(pv);
                }
            }
            #pragma unroll
            for (int msk = 1; msk <= 8; msk <<= 1)
                #pragma unroll
                for (int r = 0; r < 4; ++r)
                    rowsum[r] += __shfl_xor(rowsum[r], msk, 64);
            #pragma unroll
            for (int r = 0; r < 4; ++r) ls[rg][r] = ls[rg][r] * corr[r] + rowsum[r];
            #pragma unroll
            for (int ni = 0; ni < 4; ++ni)
                #pragma unroll
                for (int r = 0; r < 4; ++r)
                    oacc[rg][ni][r] *= corr[r];

            // PV: P via per-wave LDS (in-order DS pipe, no barrier)
            #pragma unroll
            for (int ks = 0; ks < 2; ++ks) {
                const int rch = (ks * 4 + qd) ^ (lm & 7);
                bf16x8 pa = *(const bf16x8*)&Pw[lm * 64 + rch * 8];
                #pragma unroll
                for (int ni = 0; ni < 4; ++ni) {
                    const int d = ni * 16 + lm;
                    const int cj = kt * 8 + ks * 4 + qd;
                    const int pos = (cj & 16) | ((cj ^ (d & 15)) & 15);
                    bf16x8 bv = *(const bf16x8*)&R0[d * 256 + pos * 8];
                    oacc[rg][ni] = __builtin_amdgcn_mfma_f32_16x16x32_bf16(
                        pa, bv, oacc[rg][ni], 0, 0, 0);
                }
            }
        }
    }

    // ---- Phase 4: rescale, transpose via LDS, coalesced stores ------------
    __syncthreads();
    u16 (*yt)[72] = (u16(*)[72])SM;     // 256x72 u16 = 36 KB (R0 + head of R1)
    #pragma unroll
    for (int rg = 0; rg < 2; ++rg) {
        const int trow = (rg ? trg1 : trg0) + qd * 4;
        #pragma unroll
        for (int r = 0; r < 4; ++r) {
            const float inv = 1.f / ls[rg][r];
            #pragma unroll
            for (int ni = 0; ni < 4; ++ni)
                yt[trow + r][ni * 16 + lm] = f2b(oacc[rg][ni][r] * inv);
        }
    }
    __syncthreads();
    #pragma unroll
    for (int rr = 0; rr < 4; ++rr) {
        const int row = rr * 64 + (tid >> 3);
        const int col = (tid & 7) * 8;
        bf16x8 vv = *(const bf16x8*)&yt[row][col];
        *(bf16x8*)(yb + ((size_t)(b * T_ + row)) * C_ + h * 64 + col) = vv;
    }
}

// ---------------------------------------------------------------------------
// Kernel 3: output projection.  yb[32768x384] @ wpb^T + bp -> fp32 out.
// 512 threads, 256x128 tile, XCD-affine, fp32 LDS-transpose epilogue.
// ---------------------------------------------------------------------------
__global__ __launch_bounds__(512, 4) void gemm_proj(
    const u16* __restrict__ yb, const u16* __restrict__ wpb,
    const float* __restrict__ bp, float* __restrict__ out)
{
    __shared__ __align__(16) u16 SMEM[256 * 64 + 128 * 64];   // 48 KB
    u16* As = SMEM;
    u16* Bs = SMEM + 256 * 64;

    const int gid  = blockIdx.x;
    const int xcd  = gid & 7;
    const int j_   = gid >> 3;            // 0..47
    const int colb = j_ % 3;
    const int rowb = (j_ / 3) * 8 + xcd;  // 0..127
    const int m0g  = rowb * 256;
    const int n0g  = colb * 128;

    const int tid = threadIdx.x;
    const int w = tid >> 6, lane = tid & 63;
    const int lm = lane & 15, qd = lane >> 4;
    const int wm = (w >> 1) * 64, wn = (w & 1) * 64;

    const int schunk = (lane & 7) ^ ((lane >> 3) & 7);
    const u16* gA = yb  + (size_t)(m0g + w * 32 + (lane >> 3)) * C_ + schunk * 8;
    const u16* gB = wpb + (size_t)(n0g + w * 16 + (lane >> 3)) * C_ + schunk * 8;
    u16* lA = &As[(w * 32) * 64];
    u16* lB = &Bs[(w * 16) * 64];

    f32x4 acc[4][4];
    #pragma unroll
    for (int mi = 0; mi < 4; ++mi)
        #pragma unroll
        for (int ni = 0; ni < 4; ++ni)
            acc[mi][ni] = (f32x4){0.f, 0.f, 0.f, 0.f};

    for (int k0 = 0; k0 < C_; k0 += 64) {
        __syncthreads();
        #pragma unroll
        for (int j = 0; j < 4; ++j)
            gl2lds16(gA + j * 8 * C_, lA + j * 8 * 64);
        #pragma unroll
        for (int j = 0; j < 2; ++j)
            gl2lds16(gB + j * 8 * C_, lB + j * 8 * 64);
        gA += 64; gB += 64;
        __syncthreads();

        #pragma unroll
        for (int ks = 0; ks < 2; ++ks) {
            bf16x8 af[4], bfr[4];
            #pragma unroll
            for (int mi = 0; mi < 4; ++mi) {
                const int row = wm + mi * 16 + lm;
                const int sl = (ks * 4 + qd) ^ (lm & 7);
                af[mi] = *(const bf16x8*)&As[row * 64 + sl * 8];
            }
            #pragma unroll
            for (int ni = 0; ni < 4; ++ni) {
                const int row = wn + ni * 16 + lm;
                const int sl = (ks * 4 + qd) ^ (lm & 7);
                bfr[ni] = *(const bf16x8*)&Bs[row * 64 + sl * 8];
            }
            #pragma unroll
            for (int mi = 0; mi < 4; ++mi)
                #pragma unroll
                for (int ni = 0; ni < 4; ++ni)
                    acc[mi][ni] = __builtin_amdgcn_mfma_f32_16x16x32_bf16(
                        af[mi], bfr[ni], acc[mi][ni], 0, 0, 0);
        }
    }

    // fp32 LDS-transpose epilogue with fused bias
    float bpv[4];
    #pragma unroll
    for (int ni = 0; ni < 4; ++ni) bpv[ni] = bp[n0g + wn + ni * 16 + lm];

    float (*tb)[132] = (float(*)[132])SMEM;   // 64x132 f32 = 33.8 KB <= 48 KB
    const int rloc = tid >> 3;                // 0..63
    #pragma unroll
    for (int mi = 0; mi < 4; ++mi) {
        __syncthreads();
        #pragma unroll
        for (int ni = 0; ni < 4; ++ni)
            #pragma unroll
            for (int r = 0; r < 4; ++r)
                tb[(w >> 1) * 16 + qd * 4 + r][wn + ni * 16 + lm]
                    = acc[mi][ni][r] + bpv[ni];
        __syncthreads();
        const int m = m0g + (rloc >> 4) * 64 + mi * 16 + (rloc & 15);
        #pragma unroll
        for (int jj = 0; jj < 4; ++jj) {
            const int cc = (tid & 7) * 4 + jj * 32;
            float4 vv = *(const float4*)&tb[rloc][cc];
            *(float4*)(out + (size_t)m * C_ + n0g + cc) = vv;
        }
    }
}

// ---------------------------------------------------------------------------
extern "C" void kernel_launch(void* const* d_in, const int* in_sizes, int n_in,
                              void* d_out, int out_size, void* d_ws, size_t ws_size,
                              hipStream_t stream)
{
    const float* x  = (const float*)d_in[0];
    const float* Wq = (const float*)d_in[1];
    const float* Wk = (const float*)d_in[2];
    const float* Wv = (const float*)d_in[3];
    const float* Wp = (const float*)d_in[4];
    const float* bp = (const float*)d_in[5];
    float* out = (float*)d_out;

    u16* xb  = (u16*)d_ws;                         // 32768*384
    u16* wct = xb  + (size_t)NTOK * C_;            // 1152*384 (head-major)
    u16* wpb = wct + (size_t)NQKV * C_;            // 384*384
    u16* yb  = wpb + (size_t)C_ * C_;              // 32768*384

    const int prep_blocks = (J0_ + J2_ + J1_ + 255) / 256;
    hipLaunchKernelGGL(prep, dim3(prep_blocks), dim3(256), 0, stream,
                       x, Wq, Wk, Wv, Wp, xb, wct, wpb);

    hipLaunchKernelGGL(qkv_attn, dim3(B_ * H_), dim3(512), 0, stream,
                       xb, wct, yb);

    hipLaunchKernelGGL(gemm_proj, dim3((NTOK / 256) * (C_ / 128)), dim3(512), 0, stream,
                       yb, wpb, bp, out);
}

// Round 4
// 180.974 us; speedup vs baseline: 1.5648x; 1.0424x over previous
//
#include <hip/hip_runtime.h>
#include <hip/hip_bf16.h>
#include <math.h>

#define B_   128
#define T_   256
#define C_   384
#define H_   6
#define HS_  64
#define NTOK (B_*T_)          // 32768
#define NQKV (3*C_)           // 1152

typedef unsigned short u16;
typedef __attribute__((ext_vector_type(8))) short bf16x8;   // 8 bf16 in 4 VGPRs
typedef __attribute__((ext_vector_type(4))) float f32x4;

__device__ __forceinline__ u16 f2b(float f) {
    unsigned int u = __builtin_bit_cast(unsigned int, f);
    unsigned int r = (u + 0x7FFFu + ((u >> 16) & 1u)) >> 16;   // RNE
    return (u16)r;
}

// packed f32x2 -> bf16x2 (RNE), 1 VALU op.  lo16 = a, hi16 = b.
__device__ __forceinline__ unsigned pk2(float a, float b) {
    unsigned r;
    asm("v_cvt_pk_bf16_f32 %0, %1, %2" : "=v"(r) : "v"(a), "v"(b));
    return r;
}

__device__ __forceinline__ float fexp2(float x) {
#if __has_builtin(__builtin_amdgcn_exp2f)
    return __builtin_amdgcn_exp2f(x);
#else
    return exp2f(x);
#endif
}

// async global->LDS, 16B per lane.  LDS dst = wave-uniform base + lane*16B.
__device__ __forceinline__ void gl2lds16(const u16* g, u16* l) {
    __builtin_amdgcn_global_load_lds(
        (const __attribute__((address_space(1))) unsigned int*)g,
        (__attribute__((address_space(3))) unsigned int*)l, 16, 0, 0);
}

// log2(e) * (1/sqrt(64)) folded into q at the qkv epilogue; attn uses exp2.
#define QSCALE 0.180336880f

// ---------------------------------------------------------------------------
// Fused prep: x->bf16 (8/thread), Wp->bf16 (8/thread), Wcat_t build (1/thread)
// wct is HEAD-MAJOR: row n2 = h*192 + p*64 + d  (p in {q,k,v}).
// ---------------------------------------------------------------------------
#define J0_ (NTOK*C_/8)     // 1,572,864
#define J2_ (C_*C_/8)       // 18,432
#define J1_ (NQKV*C_)       // 442,368

__global__ __launch_bounds__(256) void prep(
    const float* __restrict__ x,  const float* __restrict__ Wq,
    const float* __restrict__ Wk, const float* __restrict__ Wv,
    const float* __restrict__ Wp,
    u16* __restrict__ xb, u16* __restrict__ wct, u16* __restrict__ wpb)
{
    int i = blockIdx.x * 256 + threadIdx.x;
    if (i < J0_) {
        const float4* s = (const float4*)x + (size_t)i * 2;
        float4 a = s[0], b = s[1];
        ushort4 o1, o2;
        o1.x = f2b(a.x); o1.y = f2b(a.y); o1.z = f2b(a.z); o1.w = f2b(a.w);
        o2.x = f2b(b.x); o2.y = f2b(b.y); o2.z = f2b(b.z); o2.w = f2b(b.w);
        ((ushort4*)xb)[(size_t)i * 2]     = o1;
        ((ushort4*)xb)[(size_t)i * 2 + 1] = o2;
    } else if (i < J0_ + J2_) {
        int j = i - J0_;
        const float4* s = (const float4*)Wp + (size_t)j * 2;
        float4 a = s[0], b = s[1];
        ushort4 o1, o2;
        o1.x = f2b(a.x); o1.y = f2b(a.y); o1.z = f2b(a.z); o1.w = f2b(a.w);
        o2.x = f2b(b.x); o2.y = f2b(b.y); o2.z = f2b(b.z); o2.w = f2b(b.w);
        ((ushort4*)wpb)[(size_t)j * 2]     = o1;
        ((ushort4*)wpb)[(size_t)j * 2 + 1] = o2;
    } else {
        int j = i - J0_ - J2_;
        if (j < J1_) {
            int n = j / C_, c = j % C_;
            int h = n / 192, rem = n % 192;       // head-major rows
            int p = rem >> 6, d = rem & 63;
            const float* W = (p == 0 ? Wq : (p == 1 ? Wk : Wv));
            wct[j] = f2b(W[(h * C_ + c) * HS_ + d]);
        }
    }
}

// ---------------------------------------------------------------------------
// Fused QKV projection + causal flash attention.  One block per (b,h).
// Occupancy is register-capped at 1 block/CU regardless of LDS (measured:
// r1/r3 both ~21% occ), so LDS+VGPRs are free -> spend on pipelining:
//   * GEMM: double-buffered staging, counted vmcnt(7) + raw s_barrier
//     (loads of step k+1 stay in flight across the whole compute of step k)
//   * attn: QK^T of tile kt+1 issued before softmax of tile kt
//   * all f32->bf16 via v_cvt_pk_bf16_f32 (halves softmax/epilogue VALU)
// LDS 128 KB: A0[32K] A1[32K] B0[24K] B1[24K] P[16K]
//   post-GEMM alias: Q->A0, V^T->A1, K->B0..B1, yt->A0..A1
// ---------------------------------------------------------------------------
__global__ __launch_bounds__(512, 2) void qkv_attn(
    const u16* __restrict__ xb, const u16* __restrict__ wct,
    u16* __restrict__ yb)
{
    __shared__ __align__(16) u16 SM[65536];       // 128 KB
    u16* A0 = SM;                  // 16384 u16
    u16* A1 = SM + 16384;
    u16* B0 = SM + 32768;          // 12288 u16
    u16* B1 = SM + 45056;
    u16* Qs = SM;                  // alias A0
    u16* Vs = SM + 16384;          // alias A1  [64][256] V^T swz
    u16* Ks = SM + 32768;          // alias B0+B1 [256][64] swz
    u16* Pr = SM + 57344;          // 8192 u16 P scratch

    const int gid = blockIdx.x;                    // 768 = 8 XCD * 96
    const int lin = (gid & 7) * 96 + (gid >> 3);   // bijective XCD swizzle
    const int b = lin / 6, h = lin % 6;

    const int tid = threadIdx.x;
    const int w = tid >> 6, lane = tid & 63;
    const int lm = lane & 15, qd = lane >> 4;
    const int wm = (w >> 1) * 64, wn = (w & 1) * 96;   // GEMM wave tile 64x96

    // ---- Phase 1: QKV GEMM, double-buffered -------------------------------
    const int schunk = (lane & 7) ^ ((lane >> 3) & 7);   // XOR store swizzle
    const u16* gA0 = xb  + (size_t)(b * T_ + w * 32 + (lane >> 3)) * C_ + schunk * 8;
    const u16* gB0 = wct + (size_t)(h * 192 + w * 24 + (lane >> 3)) * C_ + schunk * 8;
    u16* lA[2] = { A0 + (w * 32) * 64, A1 + (w * 32) * 64 };
    u16* lB[2] = { B0 + (w * 24) * 64, B1 + (w * 24) * 64 };

    f32x4 acc[4][6];
    #pragma unroll
    for (int mi = 0; mi < 4; ++mi)
        #pragma unroll
        for (int ni = 0; ni < 6; ++ni)
            acc[mi][ni] = (f32x4){0.f, 0.f, 0.f, 0.f};

    // prologue: stage steps 0 and 1 (7 loads each)
    #pragma unroll
    for (int s = 0; s < 2; ++s) {
        #pragma unroll
        for (int j = 0; j < 4; ++j)
            gl2lds16(gA0 + s * 64 + j * 8 * C_, lA[s] + j * 8 * 64);
        #pragma unroll
        for (int j = 0; j < 3; ++j)
            gl2lds16(gB0 + s * 64 + j * 8 * C_, lB[s] + j * 8 * 64);
    }

    #pragma unroll
    for (int k0i = 0; k0i < 6; ++k0i) {
        if (k0i < 5) asm volatile("s_waitcnt vmcnt(7)" ::: "memory");
        else         asm volatile("s_waitcnt vmcnt(0)" ::: "memory");
        __builtin_amdgcn_s_barrier();           // everyone's step-k data in LDS
        const u16* Ab = (k0i & 1) ? A1 : A0;
        const u16* Bb = (k0i & 1) ? B1 : B0;

        #pragma unroll
        for (int ks = 0; ks < 2; ++ks) {
            bf16x8 af[4], bfr[6];
            #pragma unroll
            for (int mi = 0; mi < 4; ++mi) {
                const int row = wm + mi * 16 + lm;
                const int sl = (ks * 4 + qd) ^ (lm & 7);
                af[mi] = *(const bf16x8*)&Ab[row * 64 + sl * 8];
            }
            #pragma unroll
            for (int ni = 0; ni < 6; ++ni) {
                const int row = wn + ni * 16 + lm;
                const int sl = (ks * 4 + qd) ^ (lm & 7);
                bfr[ni] = *(const bf16x8*)&Bb[row * 64 + sl * 8];
            }
            #pragma unroll
            for (int mi = 0; mi < 4; ++mi)
                #pragma unroll
                for (int ni = 0; ni < 6; ++ni)
                    acc[mi][ni] = __builtin_amdgcn_mfma_f32_16x16x32_bf16(
                        af[mi], bfr[ni], acc[mi][ni], 0, 0, 0);
        }
        asm volatile("" ::: "memory");
        __builtin_amdgcn_s_barrier();           // all reads of this buf done
        if (k0i < 4) {                          // stage step k0i+2 into this buf
            #pragma unroll
            for (int j = 0; j < 4; ++j)
                gl2lds16(gA0 + (k0i + 2) * 64 + j * 8 * C_, lA[k0i & 1] + j * 8 * 64);
            #pragma unroll
            for (int j = 0; j < 3; ++j)
                gl2lds16(gB0 + (k0i + 2) * 64 + j * 8 * C_, lB[k0i & 1] + j * 8 * 64);
        }
    }

    // ---- Phase 2: acc -> Q (A0), V^T (A1), K (B0+B1) ----------------------
    __syncthreads();
    const int wnu = __builtin_amdgcn_readfirstlane(wn);   // wave-uniform branch
    #pragma unroll
    for (int mi = 0; mi < 4; ++mi) {
        const int t0 = wm + mi * 16 + qd * 4;
        #pragma unroll
        for (int ni = 0; ni < 6; ++ni) {
            const int cat = wnu + ni * 16;        // 16-aligned -> category uniform
            const int n = wn + ni * 16 + lm;
            if (cat < 64) {                       // Q, scaled, row-swizzled
                unsigned p0 = pk2(acc[mi][ni][0] * QSCALE, acc[mi][ni][1] * QSCALE);
                unsigned p1 = pk2(acc[mi][ni][2] * QSCALE, acc[mi][ni][3] * QSCALE);
                #pragma unroll
                for (int r = 0; r < 4; ++r) {
                    const int t = t0 + r;
                    const unsigned pv = (r < 2) ? p0 : p1;
                    Qs[t * 64 + (((n >> 3) ^ (t & 7)) << 3) + (n & 7)]
                        = (r & 1) ? (u16)(pv >> 16) : (u16)pv;
                }
            } else if (cat < 128) {               // K, row-swizzled
                const int d = n - 64;
                unsigned p0 = pk2(acc[mi][ni][0], acc[mi][ni][1]);
                unsigned p1 = pk2(acc[mi][ni][2], acc[mi][ni][3]);
                #pragma unroll
                for (int r = 0; r < 4; ++r) {
                    const int t = t0 + r;
                    const unsigned pv = (r < 2) ? p0 : p1;
                    Ks[t * 64 + (((d >> 3) ^ (t & 7)) << 3) + (d & 7)]
                        = (r & 1) ? (u16)(pv >> 16) : (u16)pv;
                }
            } else {                              // V -> V^T[d][t], 8B packed
                const int d = n - 128;
                const int ch = t0 >> 3;           // t0 % 8 in {0,4}
                const int pos = (ch & 16) | ((ch ^ (d & 15)) & 15);
                unsigned p0 = pk2(acc[mi][ni][0], acc[mi][ni][1]);
                unsigned p1 = pk2(acc[mi][ni][2], acc[mi][ni][3]);
                unsigned* dst = (unsigned*)&Vs[d * 256 + pos * 8 + (t0 & 7)];
                dst[0] = p0; dst[1] = p1;
            }
        }
    }
    __syncthreads();

    // Q fragments to registers: wave w owns rows {w*16, 240-w*16} (+15)
    const int trg0 = w * 16;
    const int trg1 = 128 + (7 - w) * 16;
    bf16x8 aq[2][2];
    #pragma unroll
    for (int rg = 0; rg < 2; ++rg) {
        const int t = (rg ? trg1 : trg0) + lm;
        #pragma unroll
        for (int ks = 0; ks < 2; ++ks)
            aq[rg][ks] = *(const bf16x8*)
                &Qs[t * 64 + (((ks * 4 + qd) ^ (t & 7)) << 3)];
    }

    // ---- Phase 3: causal attention, all K/V in LDS ------------------------
    f32x4 oacc[2][4];
    float ms[2][4], ls[2][4];
    #pragma unroll
    for (int rg = 0; rg < 2; ++rg) {
        #pragma unroll
        for (int ni = 0; ni < 4; ++ni) oacc[rg][ni] = (f32x4){0.f, 0.f, 0.f, 0.f};
        #pragma unroll
        for (int r = 0; r < 4; ++r) { ms[rg][r] = -INFINITY; ls[rg][r] = 0.f; }
    }

    u16* Pw = Pr + w * 1024;     // 16x64 u16 per wave, chunk-XOR swizzled

#define QKT16(ST, AQ, J0V)                                                    \
    do {                                                                      \
        _Pragma("unroll")                                                     \
        for (int ni_ = 0; ni_ < 4; ++ni_) ST[ni_] = (f32x4){0.f,0.f,0.f,0.f}; \
        _Pragma("unroll")                                                     \
        for (int ks_ = 0; ks_ < 2; ++ks_) {                                   \
            _Pragma("unroll")                                                 \
            for (int ni_ = 0; ni_ < 4; ++ni_) {                               \
                const int krow_ = (J0V) + ni_ * 16 + lm;                      \
                const int sl_ = (ks_ * 4 + qd) ^ (lm & 7);                    \
                bf16x8 bk_ = *(const bf16x8*)&Ks[krow_ * 64 + sl_ * 8];       \
                ST[ni_] = __builtin_amdgcn_mfma_f32_16x16x32_bf16(            \
                    AQ[ks_], bk_, ST[ni_], 0, 0, 0);                          \
            }                                                                 \
        }                                                                     \
    } while (0)

    #pragma unroll
    for (int rg = 0; rg < 2; ++rg) {
        const int trg = rg ? trg1 : trg0;
        const int kmax = trg >> 6;

        f32x4 stc[4];
        QKT16(stc, aq[rg], 0);

        for (int kt = 0; kt <= kmax; ++kt) {
            const int j0 = kt * 64;
            const bool needmask = (kt == kmax);

            f32x4 stn[4];
            if (kt < kmax)
                QKT16(stn, aq[rg], j0 + 64);   // prefetch next tile's S

            // online softmax (base-2; q pre-scaled by log2e/8)
            float vals[4][4], rowmax[4];
            #pragma unroll
            for (int r = 0; r < 4; ++r) rowmax[r] = -INFINITY;
            #pragma unroll
            for (int ni = 0; ni < 4; ++ni) {
                const int s_g = j0 + ni * 16 + lm;
                #pragma unroll
                for (int r = 0; r < 4; ++r) {
                    float sc = stc[ni][r];
                    if (needmask) {
                        const int t_g = trg + qd * 4 + r;
                        sc = (s_g > t_g) ? -1e30f : sc;
                    }
                    vals[ni][r] = sc;
                    rowmax[r] = fmaxf(rowmax[r], sc);
                }
            }
            #pragma unroll
            for (int msk = 1; msk <= 8; msk <<= 1)
                #pragma unroll
                for (int r = 0; r < 4; ++r)
                    rowmax[r] = fmaxf(rowmax[r], __shfl_xor(rowmax[r], msk, 64));

            float corr[4], rowsum[4];
            #pragma unroll
            for (int r = 0; r < 4; ++r) {
                const float mn = fmaxf(ms[rg][r], rowmax[r]);
                corr[r] = fexp2(ms[rg][r] - mn);
                ms[rg][r] = mn;
                rowsum[r] = 0.f;
            }
            #pragma unroll
            for (int ni = 0; ni < 4; ++ni) {
                float pv[4];
                #pragma unroll
                for (int r = 0; r < 4; ++r) {
                    pv[r] = fexp2(vals[ni][r] - ms[rg][r]);
                    rowsum[r] += pv[r];
                }
                const int pcol = ni * 16 + lm;
                unsigned p01 = pk2(pv[0], pv[1]);
                unsigned p23 = pk2(pv[2], pv[3]);
                #pragma unroll
                for (int r = 0; r < 4; ++r) {
                    const int prow = qd * 4 + r;
                    const unsigned pp = (r < 2) ? p01 : p23;
                    Pw[prow * 64 + (((pcol >> 3) ^ (prow & 7)) << 3) + (pcol & 7)]
                        = (r & 1) ? (u16)(pp >> 16) : (u16)pp;
                }
            }
            #pragma unroll
            for (int msk = 1; msk <= 8; msk <<= 1)
                #pragma unroll
                for (int r = 0; r < 4; ++r)
                    rowsum[r] += __shfl_xor(rowsum[r], msk, 64);
            #pragma unroll
            for (int r = 0; r < 4; ++r) ls[rg][r] = ls[rg][r] * corr[r] + rowsum[r];
            #pragma unroll
            for (int ni = 0; ni < 4; ++ni)
                #pragma unroll
                for (int r = 0; r < 4; ++r)
                    oacc[rg][ni][r] *= corr[r];

            // PV: P via per-wave LDS (in-order DS pipe, no barrier)
            #pragma unroll
            for (int ks = 0; ks < 2; ++ks) {
                const int rch = (ks * 4 + qd) ^ (lm & 7);
                bf16x8 pa = *(const bf16x8*)&Pw[lm * 64 + rch * 8];
                #pragma unroll
                for (int ni = 0; ni < 4; ++ni) {
                    const int d = ni * 16 + lm;
                    const int cj = kt * 8 + ks * 4 + qd;
                    const int pos = (cj & 16) | ((cj ^ (d & 15)) & 15);
                    bf16x8 bv = *(const bf16x8*)&Vs[d * 256 + pos * 8];
                    oacc[rg][ni] = __builtin_amdgcn_mfma_f32_16x16x32_bf16(
                        pa, bv, oacc[rg][ni], 0, 0, 0);
                }
            }

            if (kt < kmax) {
                #pragma unroll
                for (int ni = 0; ni < 4; ++ni) stc[ni] = stn[ni];
            }
        }
    }

    // ---- Phase 4: rescale, transpose via LDS, coalesced stores ------------
    __syncthreads();
    u16 (*yt)[72] = (u16(*)[72])SM;     // 256x72 u16 = 36 KB (A0+A1 region)
    #pragma unroll
    for (int rg = 0; rg < 2; ++rg) {
        const int trow = (rg ? trg1 : trg0) + qd * 4;
        float inv[4];
        #pragma unroll
        for (int r = 0; r < 4; ++r) inv[r] = __builtin_amdgcn_rcpf(ls[rg][r]);
        #pragma unroll
        for (int ni = 0; ni < 4; ++ni) {
            unsigned p01 = pk2(oacc[rg][ni][0] * inv[0], oacc[rg][ni][1] * inv[1]);
            unsigned p23 = pk2(oacc[rg][ni][2] * inv[2], oacc[rg][ni][3] * inv[3]);
            #pragma unroll
            for (int r = 0; r < 4; ++r) {
                const unsigned pp = (r < 2) ? p01 : p23;
                yt[trow + r][ni * 16 + lm] = (r & 1) ? (u16)(pp >> 16) : (u16)pp;
            }
        }
    }
    __syncthreads();
    #pragma unroll
    for (int rr = 0; rr < 4; ++rr) {
        const int row = rr * 64 + (tid >> 3);
        const int col = (tid & 7) * 8;
        bf16x8 vv = *(const bf16x8*)&yt[row][col];
        *(bf16x8*)(yb + ((size_t)(b * T_ + row)) * C_ + h * 64 + col) = vv;
    }
}

// ---------------------------------------------------------------------------
// Kernel 3: output projection.  yb[32768x384] @ wpb^T + bp -> fp32 out.
// 512 threads, 256x128 tile, XCD-affine, fp32 LDS-transpose epilogue.
// ---------------------------------------------------------------------------
__global__ __launch_bounds__(512, 4) void gemm_proj(
    const u16* __restrict__ yb, const u16* __restrict__ wpb,
    const float* __restrict__ bp, float* __restrict__ out)
{
    __shared__ __align__(16) u16 SMEM[256 * 64 + 128 * 64];   // 48 KB
    u16* As = SMEM;
    u16* Bs = SMEM + 256 * 64;

    const int gid  = blockIdx.x;
    const int xcd  = gid & 7;
    const int j_   = gid >> 3;            // 0..47
    const int colb = j_ % 3;
    const int rowb = (j_ / 3) * 8 + xcd;  // 0..127
    const int m0g  = rowb * 256;
    const int n0g  = colb * 128;

    const int tid = threadIdx.x;
    const int w = tid >> 6, lane = tid & 63;
    const int lm = lane & 15, qd = lane >> 4;
    const int wm = (w >> 1) * 64, wn = (w & 1) * 64;

    const int schunk = (lane & 7) ^ ((lane >> 3) & 7);
    const u16* gA = yb  + (size_t)(m0g + w * 32 + (lane >> 3)) * C_ + schunk * 8;
    const u16* gB = wpb + (size_t)(n0g + w * 16 + (lane >> 3)) * C_ + schunk * 8;
    u16* lA = &As[(w * 32) * 64];
    u16* lB = &Bs[(w * 16) * 64];

    f32x4 acc[4][4];
    #pragma unroll
    for (int mi = 0; mi < 4; ++mi)
        #pragma unroll
        for (int ni = 0; ni < 4; ++ni)
            acc[mi][ni] = (f32x4){0.f, 0.f, 0.f, 0.f};

    for (int k0 = 0; k0 < C_; k0 += 64) {
        __syncthreads();
        #pragma unroll
        for (int j = 0; j < 4; ++j)
            gl2lds16(gA + j * 8 * C_, lA + j * 8 * 64);
        #pragma unroll
        for (int j = 0; j < 2; ++j)
            gl2lds16(gB + j * 8 * C_, lB + j * 8 * 64);
        gA += 64; gB += 64;
        __syncthreads();

        #pragma unroll
        for (int ks = 0; ks < 2; ++ks) {
            bf16x8 af[4], bfr[4];
            #pragma unroll
            for (int mi = 0; mi < 4; ++mi) {
                const int row = wm + mi * 16 + lm;
                const int sl = (ks * 4 + qd) ^ (lm & 7);
                af[mi] = *(const bf16x8*)&As[row * 64 + sl * 8];
            }
            #pragma unroll
            for (int ni = 0; ni < 4; ++ni) {
                const int row = wn + ni * 16 + lm;
                const int sl = (ks * 4 + qd) ^ (lm & 7);
                bfr[ni] = *(const bf16x8*)&Bs[row * 64 + sl * 8];
            }
            #pragma unroll
            for (int mi = 0; mi < 4; ++mi)
                #pragma unroll
                for (int ni = 0; ni < 4; ++ni)
                    acc[mi][ni] = __builtin_amdgcn_mfma_f32_16x16x32_bf16(
                        af[mi], bfr[ni], acc[mi][ni], 0, 0, 0);
        }
    }

    // fp32 LDS-transpose epilogue with fused bias
    float bpv[4];
    #pragma unroll
    for (int ni = 0; ni < 4; ++ni) bpv[ni] = bp[n0g + wn + ni * 16 + lm];

    float (*tb)[132] = (float(*)[132])SMEM;   // 64x132 f32 = 33.8 KB <= 48 KB
    const int rloc = tid >> 3;                // 0..63
    #pragma unroll
    for (int mi = 0; mi < 4; ++mi) {
        __syncthreads();
        #pragma unroll
        for (int ni = 0; ni < 4; ++ni)
            #pragma unroll
            for (int r = 0; r < 4; ++r)
                tb[(w >> 1) * 16 + qd * 4 + r][wn + ni * 16 + lm]
                    = acc[mi][ni][r] + bpv[ni];
        __syncthreads();
        const int m = m0g + (rloc >> 4) * 64 + mi * 16 + (rloc & 15);
        #pragma unroll
        for (int jj = 0; jj < 4; ++jj) {
            const int cc = (tid & 7) * 4 + jj * 32;
            float4 vv = *(const float4*)&tb[rloc][cc];
            *(float4*)(out + (size_t)m * C_ + n0g + cc) = vv;
        }
    }
}

// ---------------------------------------------------------------------------
extern "C" void kernel_launch(void* const* d_in, const int* in_sizes, int n_in,
                              void* d_out, int out_size, void* d_ws, size_t ws_size,
                              hipStream_t stream)
{
    const float* x  = (const float*)d_in[0];
    const float* Wq = (const float*)d_in[1];
    const float* Wk = (const float*)d_in[2];
    const float* Wv = (const float*)d_in[3];
    const float* Wp = (const float*)d_in[4];
    const float* bp = (const float*)d_in[5];
    float* out = (float*)d_out;

    u16* xb  = (u16*)d_ws;                         // 32768*384
    u16* wct = xb  + (size_t)NTOK * C_;            // 1152*384 (head-major)
    u16* wpb = wct + (size_t)NQKV * C_;            // 384*384
    u16* yb  = wpb + (size_t)C_ * C_;              // 32768*384

    const int prep_blocks = (J0_ + J2_ + J1_ + 255) / 256;
    hipLaunchKernelGGL(prep, dim3(prep_blocks), dim3(256), 0, stream,
                       x, Wq, Wk, Wv, Wp, xb, wct, wpb);

    hipLaunchKernelGGL(qkv_attn, dim3(B_ * H_), dim3(512), 0, stream,
                       xb, wct, yb);

    hipLaunchKernelGGL(gemm_proj, dim3((NTOK / 256) * (C_ / 128)), dim3(512), 0, stream,
                       yb, wpb, bp, out);
}